// Round 1
// baseline (3799.554 us; speedup 1.0000x reference)
//
#include <hip/hip_runtime.h>

// LayerRouter: x[M,H] @ w1[H,MID] -> relu -> @ w2[MID,8] -> softmax -> top2
// -> normalized soft mask [M,8] + aux loss scalar.
// M = B*S = 16384, H = 4096, MID = 2048, E = 8. All fp32.
//
// Round 1: correct fp32 baseline. GEMM1 (the 275 GFLOP cost) tiled 64x64x16,
// with GEMM2 fused into the epilogue via shuffle-reduce + global atomicAdd
// into a logits[M,8] buffer in workspace. No fp32 MFMA exists on CDNA4;
// this is VALU-bound by design this round.

#define TM 64
#define TN 64
#define BK 16
#define NE 8

__global__ __launch_bounds__(256) void gemm1_fused(
    const float* __restrict__ x,    // [M, K] row-major
    const float* __restrict__ w1,   // [K, N] row-major
    const float* __restrict__ b1,   // [N]
    const float* __restrict__ w2,   // [N, NE] row-major
    float* __restrict__ logits,     // [M, NE] (pre-zeroed, atomic accumulate)
    int M, int K, int N)
{
    __shared__ float As[BK][TM + 4];   // transposed: As[k][m]; +4 keeps 16B align
    __shared__ float Bs[BK][TN];       // Bs[k][n]

    const int tid = threadIdx.x;       // 0..255
    const int tx  = tid & 15;          // col-group 0..15
    const int ty  = tid >> 4;          // row-group 0..15
    const int n0  = blockIdx.x * TN;
    const int m0  = blockIdx.y * TM;

    // load mappings
    const int a_k = tid & 15;          // k within tile
    const int a_r = tid >> 4;          // row (16 rows/pass, 4 passes)
    const int b_n = tid & 63;          // n within tile
    const int b_k = tid >> 6;          // k (4 k/pass, 4 passes)

    float acc[4][4] = {};

    for (int k0 = 0; k0 < K; k0 += BK) {
        #pragma unroll
        for (int p = 0; p < 4; ++p) {
            int r = a_r + 16 * p;
            As[a_k][r] = x[(size_t)(m0 + r) * K + (k0 + a_k)];
        }
        #pragma unroll
        for (int p = 0; p < 4; ++p) {
            int k = b_k + 4 * p;
            Bs[k][b_n] = w1[(size_t)(k0 + k) * N + (n0 + b_n)];
        }
        __syncthreads();

        #pragma unroll
        for (int k = 0; k < BK; ++k) {
            float a[4], b[4];
            #pragma unroll
            for (int i = 0; i < 4; ++i) a[i] = As[k][ty * 4 + i];
            #pragma unroll
            for (int j = 0; j < 4; ++j) b[j] = Bs[k][tx * 4 + j];
            #pragma unroll
            for (int i = 0; i < 4; ++i)
                #pragma unroll
                for (int j = 0; j < 4; ++j)
                    acc[i][j] = fmaf(a[i], b[j], acc[i][j]);
        }
        __syncthreads();
    }

    // Epilogue: relu(acc + b1) then contract with w2 -> partial logits.
    float part[4][NE];
    #pragma unroll
    for (int i = 0; i < 4; ++i)
        #pragma unroll
        for (int e = 0; e < NE; ++e) part[i][e] = 0.f;

    #pragma unroll
    for (int j = 0; j < 4; ++j) {
        int n = n0 + tx * 4 + j;
        float bias = b1[n];
        float4 wlo = *(const float4*)&w2[(size_t)n * NE + 0];
        float4 whi = *(const float4*)&w2[(size_t)n * NE + 4];
        #pragma unroll
        for (int i = 0; i < 4; ++i) {
            float h = acc[i][j] + bias;
            h = h > 0.f ? h : 0.f;
            part[i][0] = fmaf(h, wlo.x, part[i][0]);
            part[i][1] = fmaf(h, wlo.y, part[i][1]);
            part[i][2] = fmaf(h, wlo.z, part[i][2]);
            part[i][3] = fmaf(h, wlo.w, part[i][3]);
            part[i][4] = fmaf(h, whi.x, part[i][4]);
            part[i][5] = fmaf(h, whi.y, part[i][5]);
            part[i][6] = fmaf(h, whi.z, part[i][6]);
            part[i][7] = fmaf(h, whi.w, part[i][7]);
        }
    }

    // Reduce across the 16 tx lanes (consecutive lanes share ty).
    #pragma unroll
    for (int i = 0; i < 4; ++i)
        #pragma unroll
        for (int e = 0; e < NE; ++e) {
            float v = part[i][e];
            #pragma unroll
            for (int off = 8; off > 0; off >>= 1)
                v += __shfl_down(v, off, 16);
            part[i][e] = v;
        }

    if (tx == 0) {
        #pragma unroll
        for (int i = 0; i < 4; ++i) {
            int m = m0 + ty * 4 + i;
            #pragma unroll
            for (int e = 0; e < NE; ++e)
                atomicAdd(&logits[(size_t)m * NE + e], part[i][e]);
        }
    }
}

__global__ __launch_bounds__(256) void router_kernel(
    const float* __restrict__ logits,  // [M, NE]
    const float* __restrict__ b2,      // [NE]
    float* __restrict__ out,           // [M, NE] soft mask
    float* __restrict__ acc,           // [16]: usage_sum[8], mass_sum[8]
    int M)
{
    __shared__ float s_acc[2 * NE];
    int tid = threadIdx.x;
    if (tid < 2 * NE) s_acc[tid] = 0.f;
    __syncthreads();

    int tok = blockIdx.x * blockDim.x + tid;
    if (tok < M) {
        float4 lo = *(const float4*)&logits[(size_t)tok * NE + 0];
        float4 hi = *(const float4*)&logits[(size_t)tok * NE + 4];
        float l[NE] = { lo.x + b2[0], lo.y + b2[1], lo.z + b2[2], lo.w + b2[3],
                        hi.x + b2[4], hi.y + b2[5], hi.z + b2[6], hi.w + b2[7] };
        float mx = l[0];
        #pragma unroll
        for (int e = 1; e < NE; ++e) mx = fmaxf(mx, l[e]);
        float p[NE], s = 0.f;
        #pragma unroll
        for (int e = 0; e < NE; ++e) { p[e] = __expf(l[e] - mx); s += p[e]; }

        // top-1 then top-2 (strict > keeps lowest index on ties, matching top_k)
        int i1 = 0; float v1 = p[0];
        #pragma unroll
        for (int e = 1; e < NE; ++e) if (p[e] > v1) { v1 = p[e]; i1 = e; }
        int i2 = (i1 == 0) ? 1 : 0; float v2 = p[i2];
        #pragma unroll
        for (int e = 0; e < NE; ++e)
            if (e != i1 && p[e] > v2) { v2 = p[e]; i2 = e; }

        v1 /= s; v2 /= s;
        float denom = fmaxf(v1 + v2, 1e-8f);
        float o1 = v1 / denom, o2 = v2 / denom;

        float o[NE];
        #pragma unroll
        for (int e = 0; e < NE; ++e)
            o[e] = (e == i1) ? o1 : ((e == i2) ? o2 : 0.f);
        *(float4*)&out[(size_t)tok * NE + 0] = make_float4(o[0], o[1], o[2], o[3]);
        *(float4*)&out[(size_t)tok * NE + 4] = make_float4(o[4], o[5], o[6], o[7]);

        atomicAdd(&s_acc[i1], 1.f);
        atomicAdd(&s_acc[i2], 1.f);
        atomicAdd(&s_acc[NE + i1], o1);
        atomicAdd(&s_acc[NE + i2], o2);
    }
    __syncthreads();
    if (tid < 2 * NE) atomicAdd(&acc[tid], s_acc[tid]);
}

__global__ void aux_kernel(const float* __restrict__ acc,
                           float* __restrict__ out_aux, float invM)
{
    if (threadIdx.x == 0) {
        float s = 0.f;
        #pragma unroll
        for (int e = 0; e < NE; ++e)
            s += (acc[e] * invM) * (acc[NE + e] * invM);
        *out_aux = (float)NE * s;
    }
}

extern "C" void kernel_launch(void* const* d_in, const int* in_sizes, int n_in,
                              void* d_out, int out_size, void* d_ws, size_t ws_size,
                              hipStream_t stream)
{
    const float* x  = (const float*)d_in[0];
    const float* w1 = (const float*)d_in[1];
    const float* b1 = (const float*)d_in[2];
    const float* w2 = (const float*)d_in[3];
    const float* b2 = (const float*)d_in[4];

    const int MID = in_sizes[2];          // 2048
    const int E   = in_sizes[4];          // 8 (NE)
    const int H   = in_sizes[1] / MID;    // 4096
    const int M   = in_sizes[0] / H;      // 16384

    float* out    = (float*)d_out;
    float* logits = (float*)d_ws;                  // [M, E]
    float* acc    = logits + (size_t)M * E;        // [16]

    hipMemsetAsync(d_ws, 0, (size_t)M * E * sizeof(float) + 16 * sizeof(float),
                   stream);

    dim3 grid1(MID / TN, M / TM);
    gemm1_fused<<<grid1, 256, 0, stream>>>(x, w1, b1, w2, logits, M, H, MID);

    router_kernel<<<(M + 255) / 256, 256, 0, stream>>>(logits, b2, out, acc, M);

    aux_kernel<<<1, 64, 0, stream>>>(acc, out + (size_t)M * E, 1.0f / (float)M);
}

// Round 3
// 1471.932 us; speedup vs baseline: 2.5813x; 2.5813x over previous
//
#include <hip/hip_runtime.h>
#include <hip/hip_bf16.h>

// LayerRouter: relu(x@w1+b1)@w2 -> softmax -> top2 -> soft mask [M,8] + aux.
// M=16384, K(H)=4096, N(MID)=2048, E=8, fp32 in/out.
//
// Round 3: fix round-2 bug — A-tile staging only filled 32/128 rows
// (missing 4-pass loop). Everything else unchanged from round 2.

#define NE 8
#define BM 128
#define BN 128
#define BK 32

typedef __attribute__((ext_vector_type(8))) short bf16x8;
typedef __attribute__((ext_vector_type(4))) float f32x4;

__device__ inline ushort f2bf_rne(float v) {
    unsigned x = __float_as_uint(v);
    unsigned r = (x + 0x7fffu + ((x >> 16) & 1u)) >> 16;
    return (ushort)r;
}
__device__ inline float bf2f(ushort u) {
    return __uint_as_float(((unsigned)u) << 16);
}

// ---------------- w1 [K][N] fp32 -> w1t_hi/lo [N][K] bf16 ----------------
__global__ __launch_bounds__(256) void decomp_w1(
    const float* __restrict__ w1, ushort* __restrict__ w1t_hi,
    ushort* __restrict__ w1t_lo, int K, int N)
{
    __shared__ float tile[32][33];
    const int k0 = blockIdx.y * 32, n0 = blockIdx.x * 32;
    const int t = threadIdx.x;
    {
        int k = t >> 3, n4 = (t & 7) * 4;
        float4 v = *(const float4*)&w1[(size_t)(k0 + k) * N + n0 + n4];
        tile[k][n4 + 0] = v.x; tile[k][n4 + 1] = v.y;
        tile[k][n4 + 2] = v.z; tile[k][n4 + 3] = v.w;
    }
    __syncthreads();
    {
        int n = t >> 3, k4 = (t & 7) * 4;
        ushort4 h, l;
        float v;
        v = tile[k4 + 0][n]; h.x = f2bf_rne(v); l.x = f2bf_rne(v - bf2f(h.x));
        v = tile[k4 + 1][n]; h.y = f2bf_rne(v); l.y = f2bf_rne(v - bf2f(h.y));
        v = tile[k4 + 2][n]; h.z = f2bf_rne(v); l.z = f2bf_rne(v - bf2f(h.z));
        v = tile[k4 + 3][n]; h.w = f2bf_rne(v); l.w = f2bf_rne(v - bf2f(h.w));
        *(ushort4*)&w1t_hi[(size_t)(n0 + n) * K + k0 + k4] = h;
        *(ushort4*)&w1t_lo[(size_t)(n0 + n) * K + k0 + k4] = l;
    }
}

// ---------------- bf16x3 MFMA GEMM + fused epilogue ----------------
__global__ __launch_bounds__(256) void gemm_bf16x3(
    const float* __restrict__ x,        // [M][K]
    const ushort* __restrict__ w1t_hi,  // [N][K]
    const ushort* __restrict__ w1t_lo,  // [N][K]
    const float* __restrict__ b1,       // [N]
    const float* __restrict__ w2,       // [N][NE]
    float* __restrict__ logits,         // [M][NE] atomic accumulate
    int M, int K, int N)
{
    __shared__ ushort Ah[BM][BK], Al[BM][BK];   // 8 KB each
    __shared__ ushort Bh[BN][BK], Bl[BN][BK];   // 8 KB each

    const int t    = threadIdx.x;
    const int lane = t & 63, wave = t >> 6;
    const int wm   = wave >> 1, wn = wave & 1;
    const int quad = lane >> 4, l15 = lane & 15;
    const int n0   = blockIdx.x * BN;   // N fastest: 16 n-blocks share x strip
    const int m0   = blockIdx.y * BM;

    // A staging map: thread p-th pass reads float4 x[m0+am+32p][k0+ak..+3]
    const int am = t >> 3, ak = (t & 7) * 4;
    const float* xg = &x[(size_t)(m0 + am) * K + ak];

    // B staging via global_load_lds: chunk c in [0,512): n=c>>2, koff=(c&3)*8,
    // LDS linear off = c*16 bytes. Wave handles chunks p*256 + wave*64 + lane.
    const int c0 = wave * 64 + lane;          // pass 0 chunk (== t)
    const int c1 = c0 + 256;                  // pass 1 chunk
    const size_t bg0 = (size_t)(n0 + (c0 >> 2)) * K + (size_t)(c0 & 3) * 8;
    const size_t bg1 = (size_t)(n0 + (c1 >> 2)) * K + (size_t)(c1 & 3) * 8;
    ushort* const bh_base  = &Bh[0][0] + (size_t)(wave * 64) * 8;        // pass0
    ushort* const bh_base1 = &Bh[0][0] + (size_t)(wave * 64 + 256) * 8;  // pass1
    ushort* const bl_base  = &Bl[0][0] + (size_t)(wave * 64) * 8;
    ushort* const bl_base1 = &Bl[0][0] + (size_t)(wave * 64 + 256) * 8;

    f32x4 acc[4][4] = {};

    for (int k0 = 0; k0 < K; k0 += BK) {
        __syncthreads();
        // --- B: async global->LDS, 16B chunks ---
        __builtin_amdgcn_global_load_lds(
            (const __attribute__((address_space(1))) unsigned*)(w1t_hi + bg0 + k0),
            (__attribute__((address_space(3))) unsigned*)bh_base, 16, 0, 0);
        __builtin_amdgcn_global_load_lds(
            (const __attribute__((address_space(1))) unsigned*)(w1t_hi + bg1 + k0),
            (__attribute__((address_space(3))) unsigned*)bh_base1, 16, 0, 0);
        __builtin_amdgcn_global_load_lds(
            (const __attribute__((address_space(1))) unsigned*)(w1t_lo + bg0 + k0),
            (__attribute__((address_space(3))) unsigned*)bl_base, 16, 0, 0);
        __builtin_amdgcn_global_load_lds(
            (const __attribute__((address_space(1))) unsigned*)(w1t_lo + bg1 + k0),
            (__attribute__((address_space(3))) unsigned*)bl_base1, 16, 0, 0);
        // --- A: fp32 read, split to bf16 hi/lo in registers (4 passes) ---
        #pragma unroll
        for (int p = 0; p < 4; ++p) {
            float4 v = *(const float4*)(xg + (size_t)p * 32 * K + k0);
            ushort4 h, l;
            h.x = f2bf_rne(v.x); l.x = f2bf_rne(v.x - bf2f(h.x));
            h.y = f2bf_rne(v.y); l.y = f2bf_rne(v.y - bf2f(h.y));
            h.z = f2bf_rne(v.z); l.z = f2bf_rne(v.z - bf2f(h.z));
            h.w = f2bf_rne(v.w); l.w = f2bf_rne(v.w - bf2f(h.w));
            *(ushort4*)&Ah[am + 32 * p][ak] = h;
            *(ushort4*)&Al[am + 32 * p][ak] = l;
        }
        __syncthreads();

        bf16x8 afh[4], afl[4], bfh[4], bfl[4];
        #pragma unroll
        for (int i = 0; i < 4; ++i) {
            afh[i] = *(const bf16x8*)&Ah[wm * 64 + i * 16 + l15][quad * 8];
            afl[i] = *(const bf16x8*)&Al[wm * 64 + i * 16 + l15][quad * 8];
        }
        #pragma unroll
        for (int j = 0; j < 4; ++j) {
            bfh[j] = *(const bf16x8*)&Bh[wn * 64 + j * 16 + l15][quad * 8];
            bfl[j] = *(const bf16x8*)&Bl[wn * 64 + j * 16 + l15][quad * 8];
        }
        #pragma unroll
        for (int i = 0; i < 4; ++i)
            #pragma unroll
            for (int j = 0; j < 4; ++j) {
                acc[i][j] = __builtin_amdgcn_mfma_f32_16x16x32_bf16(
                    afh[i], bfh[j], acc[i][j], 0, 0, 0);
                acc[i][j] = __builtin_amdgcn_mfma_f32_16x16x32_bf16(
                    afh[i], bfl[j], acc[i][j], 0, 0, 0);
                acc[i][j] = __builtin_amdgcn_mfma_f32_16x16x32_bf16(
                    afl[i], bfh[j], acc[i][j], 0, 0, 0);
            }
    }

    // ---- epilogue: h = relu(acc + b1); logits += h @ w2 ----
    // acc[i][j][r] is h at row = m0+wm*64+i*16+quad*4+r, col = n0+wn*64+j*16+l15
    float w2row[4][NE], b1v[4];
    #pragma unroll
    for (int j = 0; j < 4; ++j) {
        int n = n0 + wn * 64 + j * 16 + l15;
        b1v[j] = b1[n];
        float4 lo4 = *(const float4*)&w2[(size_t)n * NE + 0];
        float4 hi4 = *(const float4*)&w2[(size_t)n * NE + 4];
        w2row[j][0] = lo4.x; w2row[j][1] = lo4.y; w2row[j][2] = lo4.z; w2row[j][3] = lo4.w;
        w2row[j][4] = hi4.x; w2row[j][5] = hi4.y; w2row[j][6] = hi4.z; w2row[j][7] = hi4.w;
    }
    #pragma unroll
    for (int i = 0; i < 4; ++i) {
        #pragma unroll
        for (int r = 0; r < 4; ++r) {
            float s[NE];
            #pragma unroll
            for (int e = 0; e < NE; ++e) s[e] = 0.f;
            #pragma unroll
            for (int j = 0; j < 4; ++j) {
                float h = acc[i][j][r] + b1v[j];
                h = h > 0.f ? h : 0.f;
                #pragma unroll
                for (int e = 0; e < NE; ++e) s[e] = fmaf(h, w2row[j][e], s[e]);
            }
            #pragma unroll
            for (int e = 0; e < NE; ++e) {
                #pragma unroll
                for (int off = 8; off > 0; off >>= 1)
                    s[e] += __shfl_down(s[e], off, 16);
            }
            if (l15 == 0) {
                int m = m0 + wm * 64 + i * 16 + quad * 4 + r;
                #pragma unroll
                for (int e = 0; e < NE; ++e)
                    atomicAdd(&logits[(size_t)m * NE + e], s[e]);
            }
        }
    }
}

// ---------------- fp32 fallback GEMM (round-1, ws-size guard) ----------------
#define TM 64
#define TN 64
#define FBK 16

__global__ __launch_bounds__(256) void gemm1_fused(
    const float* __restrict__ x, const float* __restrict__ w1,
    const float* __restrict__ b1, const float* __restrict__ w2,
    float* __restrict__ logits, int M, int K, int N)
{
    __shared__ float As[FBK][TM + 4];
    __shared__ float Bs[FBK][TN];
    const int tid = threadIdx.x;
    const int tx = tid & 15, ty = tid >> 4;
    const int n0 = blockIdx.x * TN, m0 = blockIdx.y * TM;
    const int a_k = tid & 15, a_r = tid >> 4;
    const int b_n = tid & 63, b_k = tid >> 6;
    float acc[4][4] = {};
    for (int k0 = 0; k0 < K; k0 += FBK) {
        #pragma unroll
        for (int p = 0; p < 4; ++p) {
            int r = a_r + 16 * p;
            As[a_k][r] = x[(size_t)(m0 + r) * K + (k0 + a_k)];
        }
        #pragma unroll
        for (int p = 0; p < 4; ++p) {
            int k = b_k + 4 * p;
            Bs[k][b_n] = w1[(size_t)(k0 + k) * N + (n0 + b_n)];
        }
        __syncthreads();
        #pragma unroll
        for (int k = 0; k < FBK; ++k) {
            float a[4], b[4];
            #pragma unroll
            for (int i = 0; i < 4; ++i) a[i] = As[k][ty * 4 + i];
            #pragma unroll
            for (int j = 0; j < 4; ++j) b[j] = Bs[k][tx * 4 + j];
            #pragma unroll
            for (int i = 0; i < 4; ++i)
                #pragma unroll
                for (int j = 0; j < 4; ++j)
                    acc[i][j] = fmaf(a[i], b[j], acc[i][j]);
        }
        __syncthreads();
    }
    float part[4][NE];
    #pragma unroll
    for (int i = 0; i < 4; ++i)
        #pragma unroll
        for (int e = 0; e < NE; ++e) part[i][e] = 0.f;
    #pragma unroll
    for (int j = 0; j < 4; ++j) {
        int n = n0 + tx * 4 + j;
        float bias = b1[n];
        float4 wlo = *(const float4*)&w2[(size_t)n * NE + 0];
        float4 whi = *(const float4*)&w2[(size_t)n * NE + 4];
        #pragma unroll
        for (int i = 0; i < 4; ++i) {
            float h = acc[i][j] + bias;
            h = h > 0.f ? h : 0.f;
            part[i][0] = fmaf(h, wlo.x, part[i][0]);
            part[i][1] = fmaf(h, wlo.y, part[i][1]);
            part[i][2] = fmaf(h, wlo.z, part[i][2]);
            part[i][3] = fmaf(h, wlo.w, part[i][3]);
            part[i][4] = fmaf(h, whi.x, part[i][4]);
            part[i][5] = fmaf(h, whi.y, part[i][5]);
            part[i][6] = fmaf(h, whi.z, part[i][6]);
            part[i][7] = fmaf(h, whi.w, part[i][7]);
        }
    }
    #pragma unroll
    for (int i = 0; i < 4; ++i)
        #pragma unroll
        for (int e = 0; e < NE; ++e) {
            float v = part[i][e];
            #pragma unroll
            for (int off = 8; off > 0; off >>= 1) v += __shfl_down(v, off, 16);
            part[i][e] = v;
        }
    if (tx == 0)
        #pragma unroll
        for (int i = 0; i < 4; ++i) {
            int m = m0 + ty * 4 + i;
            #pragma unroll
            for (int e = 0; e < NE; ++e)
                atomicAdd(&logits[(size_t)m * NE + e], part[i][e]);
        }
}

// ---------------- router + aux ----------------
__global__ __launch_bounds__(256) void router_kernel(
    const float* __restrict__ logits, const float* __restrict__ b2,
    float* __restrict__ out, float* __restrict__ acc, int M)
{
    __shared__ float s_acc[2 * NE];
    int tid = threadIdx.x;
    if (tid < 2 * NE) s_acc[tid] = 0.f;
    __syncthreads();
    int tok = blockIdx.x * blockDim.x + tid;
    if (tok < M) {
        float4 lo = *(const float4*)&logits[(size_t)tok * NE + 0];
        float4 hi = *(const float4*)&logits[(size_t)tok * NE + 4];
        float l[NE] = { lo.x + b2[0], lo.y + b2[1], lo.z + b2[2], lo.w + b2[3],
                        hi.x + b2[4], hi.y + b2[5], hi.z + b2[6], hi.w + b2[7] };
        float mx = l[0];
        #pragma unroll
        for (int e = 1; e < NE; ++e) mx = fmaxf(mx, l[e]);
        float p[NE], s = 0.f;
        #pragma unroll
        for (int e = 0; e < NE; ++e) { p[e] = __expf(l[e] - mx); s += p[e]; }
        int i1 = 0; float v1 = p[0];
        #pragma unroll
        for (int e = 1; e < NE; ++e) if (p[e] > v1) { v1 = p[e]; i1 = e; }
        int i2 = (i1 == 0) ? 1 : 0; float v2 = p[i2];
        #pragma unroll
        for (int e = 0; e < NE; ++e)
            if (e != i1 && p[e] > v2) { v2 = p[e]; i2 = e; }
        v1 /= s; v2 /= s;
        float denom = fmaxf(v1 + v2, 1e-8f);
        float o1 = v1 / denom, o2 = v2 / denom;
        float o[NE];
        #pragma unroll
        for (int e = 0; e < NE; ++e)
            o[e] = (e == i1) ? o1 : ((e == i2) ? o2 : 0.f);
        *(float4*)&out[(size_t)tok * NE + 0] = make_float4(o[0], o[1], o[2], o[3]);
        *(float4*)&out[(size_t)tok * NE + 4] = make_float4(o[4], o[5], o[6], o[7]);
        atomicAdd(&s_acc[i1], 1.f);
        atomicAdd(&s_acc[i2], 1.f);
        atomicAdd(&s_acc[NE + i1], o1);
        atomicAdd(&s_acc[NE + i2], o2);
    }
    __syncthreads();
    if (tid < 2 * NE) atomicAdd(&acc[tid], s_acc[tid]);
}

__global__ void aux_kernel(const float* __restrict__ acc,
                           float* __restrict__ out_aux, float invM)
{
    if (threadIdx.x == 0) {
        float s = 0.f;
        #pragma unroll
        for (int e = 0; e < NE; ++e)
            s += (acc[e] * invM) * (acc[NE + e] * invM);
        *out_aux = (float)NE * s;
    }
}

extern "C" void kernel_launch(void* const* d_in, const int* in_sizes, int n_in,
                              void* d_out, int out_size, void* d_ws, size_t ws_size,
                              hipStream_t stream)
{
    const float* x  = (const float*)d_in[0];
    const float* w1 = (const float*)d_in[1];
    const float* b1 = (const float*)d_in[2];
    const float* w2 = (const float*)d_in[3];
    const float* b2 = (const float*)d_in[4];

    const int MID = in_sizes[2];         // 2048
    const int H   = in_sizes[1] / MID;   // 4096
    const int M   = in_sizes[0] / H;     // 16384

    float* out = (float*)d_out;
    char* ws = (char*)d_ws;

    size_t logits_bytes = (size_t)M * NE * sizeof(float);
    float*  logits = (float*)ws;
    float*  acc    = (float*)(ws + logits_bytes);
    size_t  off_w1h = (logits_bytes + 64 + 255) & ~(size_t)255;
    size_t  w1t_bytes = (size_t)MID * H * sizeof(ushort);
    ushort* w1t_hi = (ushort*)(ws + off_w1h);
    ushort* w1t_lo = (ushort*)(ws + off_w1h + w1t_bytes);
    size_t  need = off_w1h + 2 * w1t_bytes;

    hipMemsetAsync(d_ws, 0, logits_bytes + 64, stream);

    if (ws_size >= need) {
        dim3 gridT(MID / 32, H / 32);
        decomp_w1<<<gridT, 256, 0, stream>>>(w1, w1t_hi, w1t_lo, H, MID);
        dim3 grid1(MID / BN, M / BM);   // N fastest -> x-strip L2 reuse
        gemm_bf16x3<<<grid1, 256, 0, stream>>>(x, w1t_hi, w1t_lo, b1, w2,
                                               logits, M, H, MID);
    } else {
        dim3 grid1(MID / TN, M / TM);
        gemm1_fused<<<grid1, 256, 0, stream>>>(x, w1, b1, w2, logits, M, H, MID);
    }

    router_kernel<<<(M + 255) / 256, 256, 0, stream>>>(logits, b2, out, acc, M);
    aux_kernel<<<1, 64, 0, stream>>>(acc, out + (size_t)M * NE, 1.0f / (float)M);
}